// Round 3
// baseline (76.277 us; speedup 1.0000x reference)
//
#include <hip/hip_runtime.h>
#include <hip/hip_bf16.h>
#include <stdint.h>

// N=M=8192, D=128. loss = mean_i[ ln(sum_j exp(-t*d_ij)) + t*d_i,lab ]
#define NR 8192
#define MC 8192
#define DD 128
#define MSPLIT 16          // column splits
#define CPB 512            // cols per block
#define TILES 16           // 32-col tiles per block
#define ROWBLK 128         // rows per block (4 waves x 32)

typedef __attribute__((ext_vector_type(8))) short short8;    // 8 bf16 (4 VGPR) MFMA frag
typedef __attribute__((ext_vector_type(16))) float f32x16;   // 32x32 MFMA C/D

__device__ __forceinline__ ushort bf16r(float f) {
    __hip_bfloat16 h = __float2bfloat16(f);
    return *(ushort*)&h;
}

// async global->LDS, 16B per lane; dest = wave-uniform base + lane*16 (HW)
__device__ __forceinline__ void gload_lds16(const void* g, void* l) {
    __builtin_amdgcn_global_load_lds(
        (const __attribute__((address_space(1))) uint32_t*)g,
        (__attribute__((address_space(3))) uint32_t*)l, 16, 0, 0);
}

// ---------------- prep: two roles in one launch ----------------
// blocks [0,2048): wave-per-row: bf16 A rows, c^2-scaled norms, picked dist, consts
// blocks [2048,2560): thread-per-16B-chunk: B repacked into MFMA-fragment order
//   f2bf chunk id = ((tile*8 + ks)*64 + slot): col = tile*32+(slot&31), k = ks*16+(slot>>5)*8
__global__ __launch_bounds__(256) void prep_kernel(
    const float* __restrict__ feat, const float* __restrict__ feat2,
    const float* __restrict__ temp_p, const int* __restrict__ labels,
    ushort* __restrict__ fb, ushort* __restrict__ f2bf,
    float* __restrict__ xsq2, float* __restrict__ ysq2,
    float* __restrict__ pick, float* __restrict__ consts) {
    int b = blockIdx.x;
    if (b < 2048) {
        int row = b * 4 + (threadIdx.x >> 6);
        int l = threadIdx.x & 63;
        float temp = *temp_p;
        float c = temp * 1.4426950408889634f;    // temp*log2(e)
        float c2 = c * c;
        int lab = labels[row];
        float2 x = ((const float2*)(feat  + (size_t)row * DD))[l];
        float2 y = ((const float2*)(feat2 + (size_t)row * DD))[l];
        float2 z = ((const float2*)(feat2 + (size_t)lab * DD))[l];
        ushort2 ux; ux.x = bf16r(x.x); ux.y = bf16r(x.y);
        ((ushort2*)(fb + (size_t)row * DD))[l] = ux;
        float sx = x.x * x.x + x.y * x.y;
        float sy = y.x * y.x + y.y * y.y;
        float d0 = x.x - z.x, d1 = x.y - z.y;
        float sd = d0 * d0 + d1 * d1;
        #pragma unroll
        for (int off = 1; off < 64; off <<= 1) {
            sx += __shfl_xor(sx, off);
            sy += __shfl_xor(sy, off);
            sd += __shfl_xor(sd, off);
        }
        if (l == 0) {
            xsq2[row] = c2 * sx;
            ysq2[row] = c2 * sy;
            pick[row] = temp * __builtin_amdgcn_sqrtf(sd);
            if (row == 0) consts[0] = -2.0f * c2;
        }
    } else {
        int id = (b - 2048) * 256 + threadIdx.x;   // 0..131071 chunk index
        int slot = id & 63;
        int ks = (id >> 6) & 7;
        int tile = id >> 9;
        int col = tile * 32 + (slot & 31);
        int k0 = ks * 16 + (slot >> 5) * 8;
        const float* src = feat2 + (size_t)col * DD + k0;
        float4 v0 = ((const float4*)src)[0];
        float4 v1 = ((const float4*)src)[1];
        short8 o;
        o[0] = (short)bf16r(v0.x); o[1] = (short)bf16r(v0.y);
        o[2] = (short)bf16r(v0.z); o[3] = (short)bf16r(v0.w);
        o[4] = (short)bf16r(v1.x); o[5] = (short)bf16r(v1.y);
        o[6] = (short)bf16r(v1.z); o[7] = (short)bf16r(v1.w);
        ((short8*)f2bf)[id] = o;
    }
}

// ---------------- main: LDS-staged B (async), register A, fused epilogue ----------------
// grid 1024 = 64 rowblocks x 16 colsplits; 4 waves; exactly 4 blocks/CU (one generation).
// Per wave: 32 rows x 512 cols. B staged double-buffered via global_load_lds (2x1KB/wave/tile),
// counted vmcnt(2) -> loads stay in flight across barriers; linear frag-ordered LDS -> 0 conflicts.
__global__ __launch_bounds__(256, 4) void main_kernel(
    const ushort* __restrict__ fb, const ushort* __restrict__ f2bf,
    const float* __restrict__ xsq2, const float* __restrict__ ysq2,
    const float* __restrict__ consts, float* __restrict__ spart) {
    __shared__ ushort lds[2][8 * 512];   // 2 x 8KB

    int bid = blockIdx.x;
    int cs = bid & (MSPLIT - 1);
    int rb = bid >> 4;
    int tid = threadIdx.x;
    int wave = tid >> 6, lane = tid & 63;
    int lcol = lane & 31, lhalf = lane >> 5;
    int rowbase = rb * ROWBLK + wave * 32;
    float m2c2 = consts[0];              // -2*c^2

    // A fragments (whole K) in registers
    short8 a[8];
    const ushort* ap = fb + (size_t)(rowbase + lcol) * DD + lhalf * 8;
    #pragma unroll
    for (int ks = 0; ks < 8; ++ks) a[ks] = *(const short8*)(ap + ks * 16);

    // c^2-scaled norms: rows of this lane's C fragment, and col norms per tile
    float xs2[16], ys2[16];
    #pragma unroll
    for (int r = 0; r < 16; ++r)
        xs2[r] = xsq2[rowbase + (r & 3) + 8 * (r >> 2) + 4 * lhalf];
    #pragma unroll
    for (int t = 0; t < TILES; ++t)
        ys2[t] = ysq2[cs * CPB + t * 32 + lcol];

    float s[16];
    #pragma unroll
    for (int r = 0; r < 16; ++r) s[r] = 0.f;

    // stage tile 0 into buf0: wave w loads chunks {w, w+4}
    {
        const ushort* g0 = f2bf + ((size_t)(cs * TILES + 0) * 8 + wave) * 512 + lane * 8;
        gload_lds16(g0, &lds[0][wave * 512]);
        gload_lds16(g0 + 4 * 512, &lds[0][(wave + 4) * 512]);
    }

    #pragma unroll
    for (int t = 0; t < TILES; ++t) {
        if (t + 1 < TILES) {   // stage next tile into other buffer
            const ushort* g = f2bf + ((size_t)(cs * TILES + t + 1) * 8 + wave) * 512 + lane * 8;
            gload_lds16(g, &lds[(t + 1) & 1][wave * 512]);
            gload_lds16(g + 4 * 512, &lds[(t + 1) & 1][(wave + 4) * 512]);
            asm volatile("s_waitcnt vmcnt(2)" ::: "memory");   // tile-t batch complete
        } else {
            asm volatile("s_waitcnt vmcnt(0)" ::: "memory");
        }
        __builtin_amdgcn_s_barrier();

        const ushort* lb = lds[t & 1];
        f32x16 acc;
        #pragma unroll
        for (int r = 0; r < 16; ++r) acc[r] = 0.f;
        #pragma unroll
        for (int ks = 0; ks < 8; ++ks) {
            short8 bf = *(const short8*)(lb + ks * 512 + lane * 8);
            acc = __builtin_amdgcn_mfma_f32_32x32x16_bf16(a[ks], bf, acc, 0, 0, 0);
        }
        #pragma unroll
        for (int r = 0; r < 16; ++r) {
            float q = fmaf(m2c2, acc[r], xs2[r] + ys2[t]);
            q = fmaxf(q, 0.f);
            s[r] += __builtin_amdgcn_exp2f(-__builtin_amdgcn_sqrtf(q));
        }
        __builtin_amdgcn_s_barrier();   // all waves done reading buf before it is re-staged
    }

    // reduce across the 32 column-lanes (within each 32-lane half)
    #pragma unroll
    for (int off = 1; off <= 16; off <<= 1)
        #pragma unroll
        for (int r = 0; r < 16; ++r) s[r] += __shfl_xor(s[r], off);

    if (lcol == 0) {
        float* sp = spart + (size_t)cs * NR + rowbase;
        #pragma unroll
        for (int r = 0; r < 16; ++r)
            sp[(r & 3) + 8 * (r >> 2) + 4 * lhalf] = s[r];
    }
}

// ---------------- finish: per-row LSE + picked, deterministic two-stage reduce ----------------
__global__ __launch_bounds__(256) void finish1_kernel(
    const float* __restrict__ spart, const float* __restrict__ pick,
    float* __restrict__ partial) {
    __shared__ float red[4];
    int row = blockIdx.x * 256 + threadIdx.x;
    float ssum = 0.f;
    #pragma unroll
    for (int ms = 0; ms < MSPLIT; ++ms) ssum += spart[(size_t)ms * NR + row];
    float v = __builtin_amdgcn_logf(ssum) * 0.6931471805599453f + pick[row];
    #pragma unroll
    for (int off = 1; off < 64; off <<= 1) v += __shfl_xor(v, off);
    if ((threadIdx.x & 63) == 0) red[threadIdx.x >> 6] = v;
    __syncthreads();
    if (threadIdx.x == 0) partial[blockIdx.x] = red[0] + red[1] + red[2] + red[3];
}

__global__ void finish2_kernel(const float* __restrict__ partial, float* __restrict__ out) {
    float v = (threadIdx.x < 32) ? partial[threadIdx.x] : 0.f;
    #pragma unroll
    for (int off = 1; off < 64; off <<= 1) v += __shfl_xor(v, off);
    if (threadIdx.x == 0) out[0] = v * (1.0f / NR);
}

extern "C" void kernel_launch(void* const* d_in, const int* in_sizes, int n_in,
                              void* d_out, int out_size, void* d_ws, size_t ws_size,
                              hipStream_t stream) {
    const float* feat   = (const float*)d_in[0];
    const float* feat2  = (const float*)d_in[1];
    const float* temp   = (const float*)d_in[2];
    const int*   labels = (const int*)d_in[3];
    float* out = (float*)d_out;

    char* ws = (char*)d_ws;
    ushort* fb    = (ushort*)ws;                   // 2 MiB: A bf16 rows
    ushort* f2bf  = (ushort*)(ws + (2u << 20));    // 2 MiB: B fragment-ordered bf16
    float*  xsq2  = (float*)(ws + (4u << 20));     // 32 KiB
    float*  ysq2  = xsq2 + NR;                     // 32 KiB
    float*  pick  = ysq2 + MC;                     // 32 KiB
    float*  consts  = pick + NR;                   // 1
    float*  partial = consts + 16;                 // 32
    float*  spart = (float*)(ws + (5u << 20));     // 512 KiB

    prep_kernel<<<2560, 256, 0, stream>>>(feat, feat2, temp, labels,
                                          fb, f2bf, xsq2, ysq2, pick, consts);
    main_kernel<<<(NR / ROWBLK) * MSPLIT, 256, 0, stream>>>(fb, f2bf, xsq2, ysq2, consts, spart);
    finish1_kernel<<<NR / 256, 256, 0, stream>>>(spart, pick, partial);
    finish2_kernel<<<1, 64, 0, stream>>>(partial, out);
}

// Round 4
// 46.839 us; speedup vs baseline: 1.6285x; 1.6285x over previous
//
#include <hip/hip_runtime.h>
#include <hip/hip_bf16.h>
#include <stdint.h>

// N=M=8192, D=128. loss = mean_i[ ln(sum_j exp(-t*d_ij)) + t*d_i,lab ]
#define NR 8192
#define MC 8192
#define DD 128
#define MSPLIT 8           // column splits
#define CPB 1024           // cols per block
#define TILES 32           // 32-col tiles per block
#define ROWBLK 128         // rows per block (4 waves x 32)

typedef __attribute__((ext_vector_type(8))) short short8;    // 8 bf16 (4 VGPR) MFMA frag
typedef __attribute__((ext_vector_type(16))) float f32x16;   // 32x32 MFMA C/D

__device__ __forceinline__ ushort bf16r(float f) {
    __hip_bfloat16 h = __float2bfloat16(f);
    return *(ushort*)&h;
}

// async global->LDS, 16B per lane; LDS dest = wave-uniform base + lane*16 (HW rule)
__device__ __forceinline__ void gload_lds16(const void* g, void* l) {
    __builtin_amdgcn_global_load_lds(
        (const __attribute__((address_space(1))) uint32_t*)g,
        (__attribute__((address_space(3))) uint32_t*)l, 16, 0, 0);
}

// ---------------- prep: two roles in one launch ----------------
// blocks [0,2048): wave-per-row: bf16 A rows, c^2-scaled norms, picked dist, consts
// blocks [2048,2560): thread-per-16B-chunk: B repacked into MFMA-fragment order
//   f2bf chunk id = ((tile*8 + ks)*64 + slot): col = tile*32+(slot&31), k = ks*16+(slot>>5)*8
__global__ __launch_bounds__(256) void prep_kernel(
    const float* __restrict__ feat, const float* __restrict__ feat2,
    const float* __restrict__ temp_p, const int* __restrict__ labels,
    ushort* __restrict__ fb, ushort* __restrict__ f2bf,
    float* __restrict__ xsq2, float* __restrict__ ysq2,
    float* __restrict__ pick, float* __restrict__ consts) {
    int b = blockIdx.x;
    if (b < 2048) {
        int row = b * 4 + (threadIdx.x >> 6);
        int l = threadIdx.x & 63;
        float temp = *temp_p;
        float c = temp * 1.4426950408889634f;    // temp*log2(e)
        float c2 = c * c;
        int lab = labels[row];
        float2 x = ((const float2*)(feat  + (size_t)row * DD))[l];
        float2 y = ((const float2*)(feat2 + (size_t)row * DD))[l];
        float2 z = ((const float2*)(feat2 + (size_t)lab * DD))[l];
        ushort2 ux; ux.x = bf16r(x.x); ux.y = bf16r(x.y);
        ((ushort2*)(fb + (size_t)row * DD))[l] = ux;
        float sx = x.x * x.x + x.y * x.y;
        float sy = y.x * y.x + y.y * y.y;
        float d0 = x.x - z.x, d1 = x.y - z.y;
        float sd = d0 * d0 + d1 * d1;
        #pragma unroll
        for (int off = 1; off < 64; off <<= 1) {
            sx += __shfl_xor(sx, off);
            sy += __shfl_xor(sy, off);
            sd += __shfl_xor(sd, off);
        }
        if (l == 0) {
            xsq2[row] = c2 * sx;
            ysq2[row] = c2 * sy;
            pick[row] = temp * __builtin_amdgcn_sqrtf(sd);
            if (row == 0) consts[0] = -2.0f * c2;
        }
    } else {
        int id = (b - 2048) * 256 + threadIdx.x;   // 0..131071 chunk index
        int slot = id & 63;
        int ks = (id >> 6) & 7;
        int tile = id >> 9;
        int col = tile * 32 + (slot & 31);
        int k0 = ks * 16 + (slot >> 5) * 8;
        const float* src = feat2 + (size_t)col * DD + k0;
        float4 v0 = ((const float4*)src)[0];
        float4 v1 = ((const float4*)src)[1];
        short8 o;
        o[0] = (short)bf16r(v0.x); o[1] = (short)bf16r(v0.y);
        o[2] = (short)bf16r(v0.z); o[3] = (short)bf16r(v0.w);
        o[4] = (short)bf16r(v1.x); o[5] = (short)bf16r(v1.y);
        o[6] = (short)bf16r(v1.z); o[7] = (short)bf16r(v1.w);
        ((short8*)f2bf)[id] = o;
    }
}

// ---------------- main: 2-deep async LDS pipeline, register A, fused epilogue ----------------
// grid 512 = 64 rowblocks x 8 colsplits; 4 waves; exactly 2 blocks/CU (cap 256 regs, no spill).
// Per wave: 32 rows x 1024 cols, 32 tiles. B staged via global_load_lds into 4 rotating
// 8KB buffers, 2 tiles ahead; counted vmcnt(4); ONE raw s_barrier per tile (with 4 buffers
// and max 1-iter wave skew, stage target t+2 never collides with buffers t-1/t in use).
__global__ __launch_bounds__(256, 2) void main_kernel(
    const ushort* __restrict__ fb, const ushort* __restrict__ f2bf,
    const float* __restrict__ xsq2, const float* __restrict__ ysq2,
    const float* __restrict__ consts, float* __restrict__ spart) {
    __shared__ ushort lds[4][8 * 512];   // 4 x 8KB

    int bid = blockIdx.x;
    int cs = bid & (MSPLIT - 1);
    int rb = bid >> 3;
    int tid = threadIdx.x;
    int wave = tid >> 6, lane = tid & 63;
    int lcol = lane & 31, lhalf = lane >> 5;
    int rowbase = rb * ROWBLK + wave * 32;
    int tile0 = cs * TILES;              // global 32-col tile index base
    float m2c2 = consts[0];              // -2*c^2

    // A fragments (whole K) in registers: 32 VGPR
    short8 a[8];
    const ushort* ap = fb + (size_t)(rowbase + lcol) * DD + lhalf * 8;
    #pragma unroll
    for (int ks = 0; ks < 8; ++ks) a[ks] = *(const short8*)(ap + ks * 16);

    // c^2-scaled row norms for this lane's C rows
    float xs2[16];
    #pragma unroll
    for (int r = 0; r < 16; ++r)
        xs2[r] = xsq2[rowbase + (r & 3) + 8 * (r >> 2) + 4 * lhalf];

    float s[16];
    #pragma unroll
    for (int r = 0; r < 16; ++r) s[r] = 0.f;

    // stage tiles 0 and 1 (wave w loads 1KB chunks w and w+4 of each 8KB tile)
    #pragma unroll
    for (int t0 = 0; t0 < 2; ++t0) {
        const ushort* g = f2bf + ((size_t)(tile0 + t0) * 8 + wave) * 512 + lane * 8;
        gload_lds16(g, &lds[t0][wave * 512]);
        gload_lds16(g + 4 * 512, &lds[t0][(wave + 4) * 512]);
    }

    #pragma unroll 1
    for (int t = 0; t < TILES; ++t) {
        if (t + 2 < TILES) {
            const ushort* g = f2bf + ((size_t)(tile0 + t + 2) * 8 + wave) * 512 + lane * 8;
            gload_lds16(g, &lds[(t + 2) & 3][wave * 512]);
            gload_lds16(g + 4 * 512, &lds[(t + 2) & 3][(wave + 4) * 512]);
            asm volatile("s_waitcnt vmcnt(4)" ::: "memory");   // tile-t batch landed
        } else if (t + 1 < TILES) {
            asm volatile("s_waitcnt vmcnt(2)" ::: "memory");
        } else {
            asm volatile("s_waitcnt vmcnt(0)" ::: "memory");
        }
        __builtin_amdgcn_s_barrier();

        float ys2 = ysq2[cs * CPB + t * 32 + lcol];   // post-barrier: keeps vmcnt count clean
        const ushort* lb = &lds[t & 3][0];
        f32x16 acc;
        #pragma unroll
        for (int r = 0; r < 16; ++r) acc[r] = 0.f;
        #pragma unroll
        for (int ks = 0; ks < 8; ++ks) {
            short8 bf = *(const short8*)(lb + ks * 512 + lane * 8);
            acc = __builtin_amdgcn_mfma_f32_32x32x16_bf16(a[ks], bf, acc, 0, 0, 0);
        }
        #pragma unroll
        for (int r = 0; r < 16; ++r) {
            float q = fmaf(m2c2, acc[r], xs2[r] + ys2);
            q = fmaxf(q, 0.f);
            s[r] += __builtin_amdgcn_exp2f(-__builtin_amdgcn_sqrtf(q));
        }
    }

    // reduce across the 32 column-lanes (xor<32 stays within each half-wave)
    #pragma unroll
    for (int off = 1; off <= 16; off <<= 1)
        #pragma unroll
        for (int r = 0; r < 16; ++r) s[r] += __shfl_xor(s[r], off);

    if (lcol == 0) {
        float* sp = spart + (size_t)cs * NR + rowbase;
        #pragma unroll
        for (int r = 0; r < 16; ++r)
            sp[(r & 3) + 8 * (r >> 2) + 4 * lhalf] = s[r];
    }
}

// ---------------- finish: per-row LSE + picked, deterministic two-stage reduce ----------------
__global__ __launch_bounds__(256) void finish1_kernel(
    const float* __restrict__ spart, const float* __restrict__ pick,
    float* __restrict__ partial) {
    __shared__ float red[4];
    int row = blockIdx.x * 256 + threadIdx.x;
    float ssum = 0.f;
    #pragma unroll
    for (int ms = 0; ms < MSPLIT; ++ms) ssum += spart[(size_t)ms * NR + row];
    float v = __builtin_amdgcn_logf(ssum) * 0.6931471805599453f + pick[row];
    #pragma unroll
    for (int off = 1; off < 64; off <<= 1) v += __shfl_xor(v, off);
    if ((threadIdx.x & 63) == 0) red[threadIdx.x >> 6] = v;
    __syncthreads();
    if (threadIdx.x == 0) partial[blockIdx.x] = red[0] + red[1] + red[2] + red[3];
}

__global__ void finish2_kernel(const float* __restrict__ partial, float* __restrict__ out) {
    float v = (threadIdx.x < 32) ? partial[threadIdx.x] : 0.f;
    #pragma unroll
    for (int off = 1; off < 64; off <<= 1) v += __shfl_xor(v, off);
    if (threadIdx.x == 0) out[0] = v * (1.0f / NR);
}

extern "C" void kernel_launch(void* const* d_in, const int* in_sizes, int n_in,
                              void* d_out, int out_size, void* d_ws, size_t ws_size,
                              hipStream_t stream) {
    const float* feat   = (const float*)d_in[0];
    const float* feat2  = (const float*)d_in[1];
    const float* temp   = (const float*)d_in[2];
    const int*   labels = (const int*)d_in[3];
    float* out = (float*)d_out;

    char* ws = (char*)d_ws;
    ushort* fb    = (ushort*)ws;                   // 2 MiB: A bf16 rows
    ushort* f2bf  = (ushort*)(ws + (2u << 20));    // 2 MiB: B fragment-ordered bf16
    float*  xsq2  = (float*)(ws + (4u << 20));     // 32 KiB
    float*  ysq2  = xsq2 + NR;                     // 32 KiB
    float*  pick  = ysq2 + MC;                     // 32 KiB
    float*  consts  = pick + NR;                   // 1
    float*  partial = consts + 16;                 // 32
    float*  spart = (float*)(ws + (5u << 20));     // 256 KiB

    prep_kernel<<<2560, 256, 0, stream>>>(feat, feat2, temp, labels,
                                          fb, f2bf, xsq2, ysq2, pick, consts);
    main_kernel<<<(NR / ROWBLK) * MSPLIT, 256, 0, stream>>>(fb, f2bf, xsq2, ysq2, consts, spart);
    finish1_kernel<<<NR / 256, 256, 0, stream>>>(spart, pick, partial);
    finish2_kernel<<<1, 64, 0, stream>>>(partial, out);
}

// Round 5
// 43.659 us; speedup vs baseline: 1.7471x; 1.0729x over previous
//
#include <hip/hip_runtime.h>
#include <hip/hip_bf16.h>
#include <stdint.h>

// N=M=8192, D=128. loss = mean_i[ ln(sum_j exp(-t*d_ij)) + t*d_i,lab ]
#define NR 8192
#define MC 8192
#define DD 128
#define MSPLIT 16          // column splits
#define CPB 512            // cols per block
#define TILES 16           // 32-col tiles per block
#define ROWBLK 128         // rows per block (4 waves x 32)

typedef __attribute__((ext_vector_type(8))) short short8;    // 8 bf16 (4 VGPR) MFMA frag
typedef __attribute__((ext_vector_type(16))) float f32x16;   // 32x32 MFMA C/D

__device__ __forceinline__ ushort bf16r(float f) {
    __hip_bfloat16 h = __float2bfloat16(f);
    return *(ushort*)&h;
}

// async global->LDS; LDS dest = wave-uniform base + lane*size (HW rule)
__device__ __forceinline__ void gload_lds16(const void* g, void* l) {
    __builtin_amdgcn_global_load_lds(
        (const __attribute__((address_space(1))) uint32_t*)g,
        (__attribute__((address_space(3))) uint32_t*)l, 16, 0, 0);
}
__device__ __forceinline__ void gload_lds4(const void* g, void* l) {
    __builtin_amdgcn_global_load_lds(
        (const __attribute__((address_space(1))) uint32_t*)g,
        (__attribute__((address_space(3))) uint32_t*)l, 4, 0, 0);
}

// ---------------- prep: two roles in one launch ----------------
// blocks [0,2048): wave-per-row: bf16 A rows, c^2-scaled norms, picked dist, consts
// blocks [2048,2560): thread-per-16B-chunk: B repacked into MFMA-fragment order
//   f2bf chunk id = ((tile*8 + ks)*64 + slot): col = tile*32+(slot&31), k = ks*16+(slot>>5)*8
__global__ __launch_bounds__(256) void prep_kernel(
    const float* __restrict__ feat, const float* __restrict__ feat2,
    const float* __restrict__ temp_p, const int* __restrict__ labels,
    ushort* __restrict__ fb, ushort* __restrict__ f2bf,
    float* __restrict__ xsq2, float* __restrict__ ysq2,
    float* __restrict__ pick, float* __restrict__ consts) {
    int b = blockIdx.x;
    if (b < 2048) {
        int row = b * 4 + (threadIdx.x >> 6);
        int l = threadIdx.x & 63;
        float temp = *temp_p;
        float c = temp * 1.4426950408889634f;    // temp*log2(e)
        float c2 = c * c;
        int lab = labels[row];
        float2 x = ((const float2*)(feat  + (size_t)row * DD))[l];
        float2 y = ((const float2*)(feat2 + (size_t)row * DD))[l];
        float2 z = ((const float2*)(feat2 + (size_t)lab * DD))[l];
        ushort2 ux; ux.x = bf16r(x.x); ux.y = bf16r(x.y);
        ((ushort2*)(fb + (size_t)row * DD))[l] = ux;
        float sx = x.x * x.x + x.y * x.y;
        float sy = y.x * y.x + y.y * y.y;
        float d0 = x.x - z.x, d1 = x.y - z.y;
        float sd = d0 * d0 + d1 * d1;
        #pragma unroll
        for (int off = 1; off < 64; off <<= 1) {
            sx += __shfl_xor(sx, off);
            sy += __shfl_xor(sy, off);
            sd += __shfl_xor(sd, off);
        }
        if (l == 0) {
            xsq2[row] = c2 * sx;
            ysq2[row] = c2 * sy;
            pick[row] = temp * __builtin_amdgcn_sqrtf(sd);
            if (row == 0) consts[0] = -2.0f * c2;
        }
    } else {
        int id = (b - 2048) * 256 + threadIdx.x;   // 0..131071 chunk index
        int slot = id & 63;
        int ks = (id >> 6) & 7;
        int tile = id >> 9;
        int col = tile * 32 + (slot & 31);
        int k0 = ks * 16 + (slot >> 5) * 8;
        const float* src = feat2 + (size_t)col * DD + k0;
        float4 v0 = ((const float4*)src)[0];
        float4 v1 = ((const float4*)src)[1];
        short8 o;
        o[0] = (short)bf16r(v0.x); o[1] = (short)bf16r(v0.y);
        o[2] = (short)bf16r(v0.z); o[3] = (short)bf16r(v0.w);
        o[4] = (short)bf16r(v1.x); o[5] = (short)bf16r(v1.y);
        o[6] = (short)bf16r(v1.z); o[7] = (short)bf16r(v1.w);
        ((short8*)f2bf)[id] = o;
    }
}

// ---------------- main: 2-deep async LDS pipeline, register A, fused epilogue ----------------
// grid 1024 = 64 rowblocks x 16 colsplits; 4 waves; 4 blocks/CU (LDS 34KB x 4 = 136KB).
// Per wave: 32 rows x 512 cols, 16 tiles. B staged via global_load_lds into 4 rotating 8KB
// buffers, 2 tiles ahead; counted vmcnt(4); ONE raw s_barrier/tile. Col norms staged in LDS
// once (ds_read per tile, lgkm counter) so NOTHING inside the loop touches vmcnt except the
// stages -> pipeline never drains (R4 bug: global ys2 load forced vmcnt(0) every tile).
__global__ __launch_bounds__(256, 3) void main_kernel(
    const ushort* __restrict__ fb, const ushort* __restrict__ f2bf,
    const float* __restrict__ xsq2, const float* __restrict__ ysq2,
    const float* __restrict__ consts, float* __restrict__ spart) {
    __shared__ ushort lds[4][8 * 512];   // 4 x 8KB tile buffers
    __shared__ float ys_lds[CPB];        // 2KB block col-norms

    int bid = blockIdx.x;
    int cs = bid & (MSPLIT - 1);
    int rb = bid >> 4;
    int tid = threadIdx.x;
    int wave = tid >> 6, lane = tid & 63;
    int lcol = lane & 31, lhalf = lane >> 5;
    int rowbase = rb * ROWBLK + wave * 32;
    int tile0 = cs * TILES;              // global 32-col tile index base
    float m2c2 = consts[0];              // -2*c^2

    // A fragments (whole K) in registers: 32 VGPR
    short8 a[8];
    const ushort* ap = fb + (size_t)(rowbase + lcol) * DD + lhalf * 8;
    #pragma unroll
    for (int ks = 0; ks < 8; ++ks) a[ks] = *(const short8*)(ap + ks * 16);

    // c^2-scaled row norms for this lane's C rows
    float xs2[16];
    #pragma unroll
    for (int r = 0; r < 16; ++r)
        xs2[r] = xsq2[rowbase + (r & 3) + 8 * (r >> 2) + 4 * lhalf];

    float s[16];
    #pragma unroll
    for (int r = 0; r < 16; ++r) s[r] = 0.f;

    // stage col norms (oldest in vmcnt FIFO: 8 chunks of 64 floats, wave w takes w and w+4)
    {
        const float* ysrc = ysq2 + cs * CPB;
        gload_lds4(ysrc + wave * 64 + lane, &ys_lds[wave * 64]);
        gload_lds4(ysrc + (wave + 4) * 64 + lane, &ys_lds[(wave + 4) * 64]);
    }
    // stage tiles 0 and 1 (wave w loads 1KB chunks w and w+4 of each 8KB tile)
    #pragma unroll
    for (int t0 = 0; t0 < 2; ++t0) {
        const ushort* g = f2bf + ((size_t)(tile0 + t0) * 8 + wave) * 512 + lane * 8;
        gload_lds16(g, &lds[t0][wave * 512]);
        gload_lds16(g + 4 * 512, &lds[t0][(wave + 4) * 512]);
    }
    // outstanding now: ys(2) + t0(2) + t1(2) = 6 per wave

    #pragma unroll 1
    for (int t = 0; t < TILES; ++t) {
        if (t + 2 < TILES) {
            const ushort* g = f2bf + ((size_t)(tile0 + t + 2) * 8 + wave) * 512 + lane * 8;
            gload_lds16(g, &lds[(t + 2) & 3][wave * 512]);
            gload_lds16(g + 4 * 512, &lds[(t + 2) & 3][(wave + 4) * 512]);
            // 6 outstanding -> keep newest 4 (tiles t+1,t+2); current tile t (+ys at t=0) landed
            asm volatile("s_waitcnt vmcnt(4)" ::: "memory");
        } else if (t + 1 < TILES) {
            asm volatile("s_waitcnt vmcnt(2)" ::: "memory");
        } else {
            asm volatile("s_waitcnt vmcnt(0)" ::: "memory");
        }
        __builtin_amdgcn_s_barrier();

        float ys2 = ys_lds[t * 32 + lcol];   // ds_read, broadcast across halves: conflict-free
        const ushort* lb = &lds[t & 3][0];
        f32x16 acc;
        #pragma unroll
        for (int r = 0; r < 16; ++r) acc[r] = 0.f;
        #pragma unroll
        for (int ks = 0; ks < 8; ++ks) {
            short8 bf = *(const short8*)(lb + ks * 512 + lane * 8);
            acc = __builtin_amdgcn_mfma_f32_32x32x16_bf16(a[ks], bf, acc, 0, 0, 0);
        }
        #pragma unroll
        for (int r = 0; r < 16; ++r) {
            float q = fmaf(m2c2, acc[r], xs2[r] + ys2);
            q = fmaxf(q, 0.f);
            s[r] += __builtin_amdgcn_exp2f(-__builtin_amdgcn_sqrtf(q));
        }
    }

    // reduce across the 32 column-lanes (xor<32 stays within each half-wave)
    #pragma unroll
    for (int off = 1; off <= 16; off <<= 1)
        #pragma unroll
        for (int r = 0; r < 16; ++r) s[r] += __shfl_xor(s[r], off);

    if (lcol == 0) {
        float* sp = spart + (size_t)cs * NR + rowbase;
        #pragma unroll
        for (int r = 0; r < 16; ++r)
            sp[(r & 3) + 8 * (r >> 2) + 4 * lhalf] = s[r];
    }
}

// ---------------- finish: per-row LSE + picked, deterministic two-stage reduce ----------------
__global__ __launch_bounds__(256) void finish1_kernel(
    const float* __restrict__ spart, const float* __restrict__ pick,
    float* __restrict__ partial) {
    __shared__ float red[4];
    int row = blockIdx.x * 256 + threadIdx.x;
    float ssum = 0.f;
    #pragma unroll
    for (int ms = 0; ms < MSPLIT; ++ms) ssum += spart[(size_t)ms * NR + row];
    float v = __builtin_amdgcn_logf(ssum) * 0.6931471805599453f + pick[row];
    #pragma unroll
    for (int off = 1; off < 64; off <<= 1) v += __shfl_xor(v, off);
    if ((threadIdx.x & 63) == 0) red[threadIdx.x >> 6] = v;
    __syncthreads();
    if (threadIdx.x == 0) partial[blockIdx.x] = red[0] + red[1] + red[2] + red[3];
}

__global__ void finish2_kernel(const float* __restrict__ partial, float* __restrict__ out) {
    float v = (threadIdx.x < 32) ? partial[threadIdx.x] : 0.f;
    #pragma unroll
    for (int off = 1; off < 64; off <<= 1) v += __shfl_xor(v, off);
    if (threadIdx.x == 0) out[0] = v * (1.0f / NR);
}

extern "C" void kernel_launch(void* const* d_in, const int* in_sizes, int n_in,
                              void* d_out, int out_size, void* d_ws, size_t ws_size,
                              hipStream_t stream) {
    const float* feat   = (const float*)d_in[0];
    const float* feat2  = (const float*)d_in[1];
    const float* temp   = (const float*)d_in[2];
    const int*   labels = (const int*)d_in[3];
    float* out = (float*)d_out;

    char* ws = (char*)d_ws;
    ushort* fb    = (ushort*)ws;                   // 2 MiB: A bf16 rows
    ushort* f2bf  = (ushort*)(ws + (2u << 20));    // 2 MiB: B fragment-ordered bf16
    float*  xsq2  = (float*)(ws + (4u << 20));     // 32 KiB
    float*  ysq2  = xsq2 + NR;                     // 32 KiB
    float*  pick  = ysq2 + MC;                     // 32 KiB
    float*  consts  = pick + NR;                   // 1
    float*  partial = consts + 16;                 // 32
    float*  spart = (float*)(ws + (5u << 20));     // 512 KiB

    prep_kernel<<<2560, 256, 0, stream>>>(feat, feat2, temp, labels,
                                          fb, f2bf, xsq2, ysq2, pick, consts);
    main_kernel<<<(NR / ROWBLK) * MSPLIT, 256, 0, stream>>>(fb, f2bf, xsq2, ysq2, consts, spart);
    finish1_kernel<<<NR / 256, 256, 0, stream>>>(spart, pick, partial);
    finish2_kernel<<<1, 64, 0, stream>>>(partial, out);
}